// Round 10
// baseline (110.730 us; speedup 1.0000x reference)
//
#include <hip/hip_runtime.h>

// Problem constants (B=1 fixed by reference)
#define HW_TOTAL (480 * 640)           // 307200 pixels
#define NC 12                           // output channels (C-1)
#define VOX_TOTAL_C (240 * 144 * 240)   // 8,294,400 voxels (divisible by 32)

#define REC_STRIDE 16                   // floats per voxel record (64 B line)
#define NGROUPS (VOX_TOTAL_C / 4)       // 2,073,600 4-voxel groups
#define GBLOCKS (NGROUPS / 256)         // 8100 group-blocks (exact)

typedef float f32x4 __attribute__((ext_vector_type(4)));

// ---------------------------------------------------------------------------
// k1 (after 1 MB bitmap memset): scatter pixel records. REGULAR stores (R8
// lesson: NT scatter stores are 64 scattered partial-line writes per instr;
// regular stores let L2 merge the 4 16-B stores into one full dirty line).
// x reads pixel-indexed -> coalesced. bitmap bit via atomicOr (map values
// unique -> no rec conflicts; atomicOr commutative -> deterministic).
__global__ void scatter_rec_kernel(const float* __restrict__ x,
                                   const int* __restrict__ map,
                                   float* __restrict__ rec,
                                   unsigned int* __restrict__ bitmap) {
    int p = blockIdx.x * blockDim.x + threadIdx.x;
    if (p >= HW_TOTAL) return;
    int v = map[p];
    if (v <= 0) return;                 // invalid pixel (dropped)
    float vals[NC];
#pragma unroll
    for (int c = 0; c < NC; ++c)
        vals[c] = x[(size_t)(c + 1) * HW_TOTAL + p];
    f32x4* dst = (f32x4*)(rec + (size_t)v * REC_STRIDE);
    f32x4 a = {vals[0], vals[1], vals[2],  vals[3]};
    f32x4 b = {vals[4], vals[5], vals[6],  vals[7]};
    f32x4 c4 = {vals[8], vals[9], vals[10], vals[11]};
    f32x4 z = {0.f, 0.f, 0.f, 0.f};
    dst[0] = a; dst[1] = b; dst[2] = c4; dst[3] = z;   // full 64-B line
    atomicOr(&bitmap[v >> 5], 1u << (v & 31));
}

// ---------------------------------------------------------------------------
// k2: streaming gather, per-channel split (endpoint of the stream-count
// ladder: 48 streams/wave = 3 TB/s, 12 = 4.9, 4 = ~5.5, fill's 1 = 6.7).
// Block b: channel c = b%12, groups (b/12)*256 .. +255. Each wave emits ONE
// contiguous 1024-B NT store stream — exactly the fill kernel's shape.
// Valid voxels load one 4-B scalar from their rec line; the 12 dispatch-
// adjacent channel-blocks sharing a group range hit the same 64-B rec lines
// concurrently -> one HBM fetch + 11 L3 hits (rec loads cacheable ON
// PURPOSE; out stores NT: R5 = single-path stores, R7 = NT not regular).
__global__ void gather_rec_kernel(const float* __restrict__ rec,
                                  const unsigned int* __restrict__ bitmap,
                                  float* __restrict__ out) {
    const int b = blockIdx.x;
    const int c = b % NC;                            // channel 0..11
    const int g = (b / NC) * 256 + threadIdx.x;      // 4-voxel group (exact)
    unsigned int word = bitmap[g >> 3];              // 8 groups share a word
    unsigned int nib = (word >> ((g & 7) * 4)) & 0xFu;
    size_t base = (size_t)g * 4;

    f32x4 o = {0.f, 0.f, 0.f, 0.f};
    if (nib) {                                       // rare: gated loads only
        if (nib & 1u) o.x = rec[(base + 0) * REC_STRIDE + c];
        if (nib & 2u) o.y = rec[(base + 1) * REC_STRIDE + c];
        if (nib & 4u) o.z = rec[(base + 2) * REC_STRIDE + c];
        if (nib & 8u) o.w = rec[(base + 3) * REC_STRIDE + c];
    }
    // Single unconditional NT store — one full-line stream per wave.
    __builtin_nontemporal_store(o,
        (f32x4*)(out + (size_t)c * VOX_TOTAL_C + base));
}

// ---------------------------------------------------------------------------
// Fallback (only if ws_size were too small): memset + naive scatter (R1 path).
__global__ void naive_scatter_kernel(const float* __restrict__ x,
                                     const int* __restrict__ map,
                                     float* __restrict__ out) {
    int p = blockIdx.x * blockDim.x + threadIdx.x;
    if (p >= HW_TOTAL) return;
    int v = map[p];
    if (v <= 0) return;
#pragma unroll
    for (int c = 0; c < NC; ++c)
        out[(size_t)c * VOX_TOTAL_C + (size_t)v] = x[(size_t)(c + 1) * HW_TOTAL + p];
}

extern "C" void kernel_launch(void* const* d_in, const int* in_sizes, int n_in,
                              void* d_out, int out_size, void* d_ws, size_t ws_size,
                              hipStream_t stream) {
    const float* x = (const float*)d_in[0];      // (1, 13, 480, 640) f32
    const int* map = (const int*)d_in[1];        // (1, 307200) i32
    float* out = (float*)d_out;                  // (1, 12, 240, 144, 240) f32

    const size_t rec_bytes = (size_t)VOX_TOTAL_C * REC_STRIDE * sizeof(float); // 531 MB
    const size_t bitmap_bytes = VOX_TOTAL_C / 8;                               // 1.04 MB

    if (ws_size < rec_bytes + bitmap_bytes) {
        // Safety net (ws is ~1.59 GB in this harness; shouldn't trigger).
        hipMemsetAsync(out, 0, (size_t)NC * VOX_TOTAL_C * sizeof(float), stream);
        naive_scatter_kernel<<<HW_TOTAL / 256, 256, 0, stream>>>(x, map, out);
        return;
    }

    float* rec = (float*)d_ws;
    unsigned int* bitmap = (unsigned int*)((char*)d_ws + rec_bytes);

    // Zero only the bitmap (1 MB) every call; rec is gated by bitmap bits.
    hipMemsetAsync(bitmap, 0, bitmap_bytes, stream);

    scatter_rec_kernel<<<HW_TOTAL / 256, 256, 0, stream>>>(x, map, rec, bitmap);

    // gather: 12 channels x 8100 group-blocks = 97,200 blocks
    gather_rec_kernel<<<GBLOCKS * NC, 256, 0, stream>>>(rec, bitmap, out);
}

// Round 11
// 104.600 us; speedup vs baseline: 1.0586x; 1.0586x over previous
//
#include <hip/hip_runtime.h>

// Problem constants (B=1 fixed by reference)
#define HW_TOTAL (480 * 640)           // 307200 pixels
#define NC 12                           // output channels (C-1)
#define VOX_TOTAL_C (240 * 144 * 240)   // 8,294,400 voxels (divisible by 32)

#define REC_STRIDE 16                   // floats per voxel record (64 B line)
#define NGROUPS (VOX_TOTAL_C / 4)       // 2,073,600 4-voxel groups
#define TILE_GROUPS 1024                // groups per block tile
#define NTILES (NGROUPS / TILE_GROUPS)  // 2025 (exact)

typedef float f32x4 __attribute__((ext_vector_type(4)));

// ---------------------------------------------------------------------------
// k1 (after 1 MB bitmap memset): scatter pixel records. REGULAR stores (R8
// lesson: NT scatter stores are 64 scattered partial-line writes per instr;
// regular stores let L2 merge the 4 16-B stores into one full dirty line).
// x reads pixel-indexed -> coalesced. bitmap bit via atomicOr (map values
// unique -> no rec conflicts; atomicOr commutative -> deterministic).
__global__ void scatter_rec_kernel(const float* __restrict__ x,
                                   const int* __restrict__ map,
                                   float* __restrict__ rec,
                                   unsigned int* __restrict__ bitmap) {
    int p = blockIdx.x * blockDim.x + threadIdx.x;
    if (p >= HW_TOTAL) return;
    int v = map[p];
    if (v <= 0) return;                 // invalid pixel (dropped)
    float vals[NC];
#pragma unroll
    for (int c = 0; c < NC; ++c)
        vals[c] = x[(size_t)(c + 1) * HW_TOTAL + p];
    f32x4* dst = (f32x4*)(rec + (size_t)v * REC_STRIDE);
    f32x4 a = {vals[0], vals[1], vals[2],  vals[3]};
    f32x4 b = {vals[4], vals[5], vals[6],  vals[7]};
    f32x4 c4 = {vals[8], vals[9], vals[10], vals[11]};
    f32x4 z = {0.f, 0.f, 0.f, 0.f};
    dst[0] = a; dst[1] = b; dst[2] = c4; dst[3] = z;   // full 64-B line
    atomicOr(&bitmap[v >> 5], 1u << (v & 31));
}

// ---------------------------------------------------------------------------
// k2: streaming gather. cq-split (4 NT store streams/wave — R9's sweet spot:
// {48,12,4,1-burst} streams -> {147,104,96,111} us) PLUS 4 consecutive
// group-rows per thread: block owns a 1024-group tile; thread handles
// g0+{0,256,512,768}. Each wave's 4 streams are now 4 KB contiguous (4
// back-to-back 1024-B bursts) with 4 independent load->store chains (MLP) —
// the two axes (stream length, in-flight chains) where R10's single-burst
// waves fell short of the fill kernel's shape. Gated 16-B rec loads; the 3
// dispatch-adjacent cq-blocks per tile share rec lines via L3. Single
// unconditional NT store path (R5: no divergent store paths; R7: NT not
// regular so L2 stays clean for rec loads).
__global__ void gather_rec_kernel(const float* __restrict__ rec,
                                  const unsigned int* __restrict__ bitmap,
                                  float* __restrict__ out) {
    const int b = blockIdx.x;
    const int cq = b % 3;                            // channel-quad 0..2
    const int g0 = (b / 3) * TILE_GROUPS + threadIdx.x;
    const int c0 = cq * 4;
    const f32x4 z = {0.f, 0.f, 0.f, 0.f};

#pragma unroll
    for (int i = 0; i < 4; ++i) {
        const int g = g0 + i * 256;                  // 4-voxel group index
        unsigned int word = bitmap[g >> 3];          // 8 groups share a word
        unsigned int nib = (word >> ((g & 7) * 4)) & 0xFu;
        size_t base = (size_t)g * 4;

        f32x4 A[4];
        A[0] = z; A[1] = z; A[2] = z; A[3] = z;
        if (nib) {                                   // rare: gated loads only
#pragma unroll
            for (int k = 0; k < 4; ++k) {
                if (nib & (1u << k)) {
                    A[k] = *(const f32x4*)(rec + (base + (size_t)k) * REC_STRIDE
                                               + (size_t)c0);
                }
            }
        }
        // Single unconditional store path — 4 full-line NT streams per wave.
#pragma unroll
        for (int c = 0; c < 4; ++c) {
            f32x4 o = { A[0][c], A[1][c], A[2][c], A[3][c] };
            __builtin_nontemporal_store(o,
                (f32x4*)(out + (size_t)(c0 + c) * VOX_TOTAL_C + base));
        }
    }
}

// ---------------------------------------------------------------------------
// Fallback (only if ws_size were too small): memset + naive scatter (R1 path).
__global__ void naive_scatter_kernel(const float* __restrict__ x,
                                     const int* __restrict__ map,
                                     float* __restrict__ out) {
    int p = blockIdx.x * blockDim.x + threadIdx.x;
    if (p >= HW_TOTAL) return;
    int v = map[p];
    if (v <= 0) return;
#pragma unroll
    for (int c = 0; c < NC; ++c)
        out[(size_t)c * VOX_TOTAL_C + (size_t)v] = x[(size_t)(c + 1) * HW_TOTAL + p];
}

extern "C" void kernel_launch(void* const* d_in, const int* in_sizes, int n_in,
                              void* d_out, int out_size, void* d_ws, size_t ws_size,
                              hipStream_t stream) {
    const float* x = (const float*)d_in[0];      // (1, 13, 480, 640) f32
    const int* map = (const int*)d_in[1];        // (1, 307200) i32
    float* out = (float*)d_out;                  // (1, 12, 240, 144, 240) f32

    const size_t rec_bytes = (size_t)VOX_TOTAL_C * REC_STRIDE * sizeof(float); // 531 MB
    const size_t bitmap_bytes = VOX_TOTAL_C / 8;                               // 1.04 MB

    if (ws_size < rec_bytes + bitmap_bytes) {
        // Safety net (ws is ~1.59 GB in this harness; shouldn't trigger).
        hipMemsetAsync(out, 0, (size_t)NC * VOX_TOTAL_C * sizeof(float), stream);
        naive_scatter_kernel<<<HW_TOTAL / 256, 256, 0, stream>>>(x, map, out);
        return;
    }

    float* rec = (float*)d_ws;
    unsigned int* bitmap = (unsigned int*)((char*)d_ws + rec_bytes);

    // Zero only the bitmap (1 MB) every call; rec is gated by bitmap bits.
    hipMemsetAsync(bitmap, 0, bitmap_bytes, stream);

    scatter_rec_kernel<<<HW_TOTAL / 256, 256, 0, stream>>>(x, map, rec, bitmap);

    // gather: 3 channel-quads x 2025 tiles = 6075 blocks
    gather_rec_kernel<<<NTILES * 3, 256, 0, stream>>>(rec, bitmap, out);
}